// Round 14
// baseline (167.057 us; speedup 1.0000x reference)
//
#include <hip/hip_runtime.h>
#include <hip/hip_bf16.h>
#include <hip/hip_fp16.h>
#include <math.h>

#define B_  4
#define S_  4096
#define D_  1024
#define M_  (B_ * S_)   // 16384 rows
#define K_  D_          // 1024 reduction
#define L_  32          // scan chunk length
#define NC_ (S_ / L_)   // 128 chunks per sequence
#define NKT 16          // K_/64 K-tiles (BK=64)

typedef __attribute__((ext_vector_type(8))) short          bf16x8;
typedef __attribute__((ext_vector_type(8))) unsigned short u16x8;
typedef __attribute__((ext_vector_type(4))) float          f32x4;

__device__ __forceinline__ unsigned short f2bf(float f) {
    union { __hip_bfloat16 h; unsigned short u; } cv;
    cv.h = __float2bfloat16(f);
    return cv.u;
}

__device__ __forceinline__ float fast_rcp(float x) {
#if __has_builtin(__builtin_amdgcn_rcpf)
    return __builtin_amdgcn_rcpf(x);
#else
    return 1.0f / x;
#endif
}

__device__ __forceinline__ void stage16(const unsigned short* src, char* dst) {
    __builtin_amdgcn_global_load_lds(
        (const __attribute__((address_space(1))) unsigned int*)src,
        (__attribute__((address_space(3))) unsigned int*)dst, 16, 0, 0);
}

// ---------------------------------------------------------------------------
// Kernel 0: fp32 -> bf16 pre-convert, x and W in ONE launch
// ---------------------------------------------------------------------------
__global__ __launch_bounds__(256) void to_bf16_both(
    const float* __restrict__ x, const float* __restrict__ W,
    unsigned short* __restrict__ xb, unsigned short* __restrict__ Wb,
    int n8x, int n8w)
{
    int i = blockIdx.x * 256 + threadIdx.x;
    const float* src;
    unsigned short* dst;
    int j;
    if (i < n8x) { src = x; dst = xb; j = i; }
    else {
        j = i - n8x;
        if (j >= n8w) return;
        src = W; dst = Wb;
    }
    const float4* p = (const float4*)src + (size_t)j * 2;
    float4 a = p[0], b = p[1];
    u16x8 o;
    o[0] = f2bf(a.x); o[1] = f2bf(a.y); o[2] = f2bf(a.z); o[3] = f2bf(a.w);
    o[4] = f2bf(b.x); o[5] = f2bf(b.y); o[6] = f2bf(b.z); o[7] = f2bf(b.w);
    *(u16x8*)(dst + (size_t)j * 8) = o;
}

// ---------------------------------------------------------------------------
// Kernel 1: champion GEMM with B DIRECT FROM GLOBAL (no B in LDS).
// Rationale: per K-tile/CU the old kernel issued 24 ds_read_b128/thread
// (16 A + 8 B) ~ 2300 cyc on the LDS pipe vs ~1240 cyc MFMA -> LDS-bound,
// MfmaUtil capped ~48% (measured 36-38 across 6 schedule variants).
// W bf16 = 4MB, L2-resident: B frags load global->reg (16 fully-used 64B
// lines per wave-instr; bytes bit-identical to the de-swizzled LDS path).
// LDS keeps A only (2 bufs x 32KB), swizzle involution unchanged.
// Geometry: BM=256, BN=128d x {h,g}, BK=64, 8 waves (2M x 4N), wave tile
// 128m x 64c, 16x16x32 MFMA. Fused linear-domain pointwise + per-32-row
// chunk-(C,V) reduction (round-8-verified).
// B prefetch: Bb(t) at phase 0 (used phase 2), Ba(t+1) at phase 3 after
// VM0/BAR (used next phase 0) -> >=2 phases of latency cover.
// ---------------------------------------------------------------------------
__global__ __launch_bounds__(512, 2) void gemm_pointwise(
    const unsigned short* __restrict__ xb, const unsigned short* __restrict__ Wb,
    __half2* __restrict__ cvb, float2* __restrict__ CVagg)
{
    __shared__ char lds[65536];   // 2 x 32KB (A only)

    const int th   = threadIdx.x;
    const int lane = th & 63;
    const int wave = th >> 6;
    const int wm = wave >> 2;      // 0..1 -> m offset 0/128
    const int wn = wave & 3;       // 0..3 -> d offset 32*wn

    const int wg  = blockIdx.x;                    // 512 wgs, 8 XCDs
    const int swz = (wg & 7) * 64 + (wg >> 3);     // bijective XCD swizzle
    const int m0 = (swz >> 3) * 256;
    const int d0 = (swz & 7) * 128;

    f32x4 acc[8][4];
#pragma unroll
    for (int i = 0; i < 8; ++i)
#pragma unroll
        for (int j = 0; j < 4; ++j)
            acc[i][j] = (f32x4){0.f, 0.f, 0.f, 0.f};

    // A staging: 512 thr x 16B = 8KB = 128 rows per call; 4 calls per K-tile
    const int srow = th >> 2;                               // 0..127
    const int scol = (((th & 3) ^ ((th >> 3) & 3)) * 8);    // pre-swizzled col
    const unsigned short* srcA  = xb + (size_t)(m0 + srow)       * K_ + scol;
    const unsigned short* srcA2 = xb + (size_t)(m0 + 128 + srow) * K_ + scol;
    char* const wuo = lds + wave * 1024;   // wave-uniform LDS dest base

    const int lr = lane & 15;
    const int lq = lane >> 4;
    const int lkb = ((lq ^ ((lr >> 1) & 3)) * 16);            // swizzled slot
    const int aoffb = (wm * 128 + lr) * 64 + lkb;             // A frag base

    // B global bases: row d0+wn*32(+16*nj)+lr (hidden) / +D_ rows (gate),
    // per-lane k-col lq*8 within each 32-col half.
    const unsigned short* bhp = Wb + (size_t)(d0 + wn * 32 + lr) * K_ + lq * 8;
    const unsigned short* bgp = bhp + (size_t)D_ * K_;

    bf16x8 Aa[4], Ab[4], Ba[4], Bb[4];

#define BAR()  asm volatile("s_barrier" ::: "memory")
#define LGK0() asm volatile("s_waitcnt lgkmcnt(0)" ::: "memory")
#define VM0()  asm volatile("s_waitcnt vmcnt(0)" ::: "memory")

#define STAGE_A(kof, bufdst) do {                                         \
    stage16(srcA  + (kof),      (bufdst) + 0);                            \
    stage16(srcA2 + (kof),      (bufdst) + 8192);                         \
    stage16(srcA  + (kof) + 32, (bufdst) + 16384);                        \
    stage16(srcA2 + (kof) + 32, (bufdst) + 24576);                        \
  } while (0)

#define LOAD_BA(tt) do { const int kc_ = (tt) * 64;                       \
    Ba[0] = *(const bf16x8*)(bhp + kc_);                                  \
    Ba[1] = *(const bf16x8*)(bhp + 16 * K_ + kc_);                        \
    Ba[2] = *(const bf16x8*)(bgp + kc_);                                  \
    Ba[3] = *(const bf16x8*)(bgp + 16 * K_ + kc_);                        \
  } while (0)
#define LOAD_BB(tt) do { const int kc_ = (tt) * 64 + 32;                  \
    Bb[0] = *(const bf16x8*)(bhp + kc_);                                  \
    Bb[1] = *(const bf16x8*)(bhp + 16 * K_ + kc_);                        \
    Bb[2] = *(const bf16x8*)(bgp + kc_);                                  \
    Bb[3] = *(const bf16x8*)(bgp + 16 * K_ + kc_);                        \
  } while (0)

#define CLUSTER(base, AF, BF) do {                                        \
    __builtin_amdgcn_s_setprio(1);                                        \
    _Pragma("unroll")                                                     \
    for (int i_ = 0; i_ < 4; ++i_)                                        \
        _Pragma("unroll")                                                 \
        for (int j_ = 0; j_ < 4; ++j_)                                    \
            acc[(base) + i_][j_] = __builtin_amdgcn_mfma_f32_16x16x32_bf16(\
                AF[i_], BF[j_], acc[(base) + i_][j_], 0, 0, 0);           \
    __builtin_amdgcn_s_setprio(0);                                        \
  } while (0)

    // prologue: stage A(tile0) -> buf0, load Ba(0), drain, read A frags
    STAGE_A(0, wuo);
    LOAD_BA(0);
    VM0();
    BAR();
#pragma unroll
    for (int i = 0; i < 4; ++i)
        Aa[i] = *(const bf16x8*)(lds + aoffb + i * 1024);

#pragma unroll 1
    for (int t = 0; t < NKT; ++t) {
        const char* bc  = lds + (t & 1) * 32768;        // compute buf (read)
        char*       bn  = wuo + ((t + 1) & 1) * 32768;  // next buf (stage dest)
        const char* bnr = lds + ((t + 1) & 1) * 32768;  // next buf (read)
        const int kof = (t + 1) * 64;
        const bool pre = (t < NKT - 1);

        // ---- phase 0: MFMA acc[0..3] = A(mh0,k0) x B(k0) ----
#pragma unroll
        for (int i = 0; i < 4; ++i)
            Ab[i] = *(const bf16x8*)(bc + aoffb + 4096 + i * 1024);    // (mh1,k0)
        if (pre) { STAGE_A(kof, bn); }
        LOAD_BB(t);                      // used at phase 2 (~2 phases cover)
        BAR(); LGK0();
        CLUSTER(0, Aa, Ba);
        BAR();

        // ---- phase 1: MFMA acc[4..7] = A(mh1,k0) x B(k0) ----
#pragma unroll
        for (int i = 0; i < 4; ++i)
            Aa[i] = *(const bf16x8*)(bc + aoffb + 16384 + i * 1024);   // (mh0,k1)
        BAR(); LGK0();
        CLUSTER(4, Ab, Ba);
        BAR();

        // ---- phase 2: MFMA acc[0..3] = A(mh0,k1) x B(k1) ----
#pragma unroll
        for (int i = 0; i < 4; ++i)
            Ab[i] = *(const bf16x8*)(bc + aoffb + 4096 + 16384 + i * 1024);  // (mh1,k1)
        BAR(); LGK0();
        CLUSTER(0, Aa, Bb);
        BAR();

        // ---- phase 3: drain A-stage, sync bufs, prefetch, last cluster ----
        VM0();           // A-stage(t+1) issued phase 0 (3 phases old) + Bb(t)
        BAR();           // buf[(t+1)&1] now globally valid
        if (pre) {       // prefetch next tile's phase-0 operands
            LOAD_BA(t + 1);
#pragma unroll
            for (int i = 0; i < 4; ++i)
                Aa[i] = *(const bf16x8*)(bnr + aoffb + i * 1024);
        }
        CLUSTER(4, Ab, Bb);
        // no trailing barrier: next phase-0 stages into buf[t&1]; last read
        // of buf[t&1] was phase 2, sealed by its closing barrier.
    }
#undef CLUSTER
#undef LOAD_BA
#undef LOAD_BB
#undef STAGE_A
#undef BAR
#undef LGK0
#undef VM0

    // ---- epilogue: pointwise + cvb store + fused chunk-(C,V) reduction ----
    // C/D: col = lane&15 (d), row = lq*4 + reg (m). Chunk (32 rows) = mi
    // pair; compose r-fold -> lq-compose (shfl_xor 16,32) -> mi-pair.
#pragma unroll
    for (int mp = 0; mp < 4; ++mp) {          // mi pair (2mp, 2mp+1)
        float C16[2][2], V16[2][2];
#pragma unroll
        for (int hf = 0; hf < 2; ++hf) {
            const int mi = mp * 2 + hf;
#pragma unroll
            for (int nj = 0; nj < 2; ++nj) {
                float C4 = 1.0f, V4 = 0.0f;
                const int d = d0 + wn * 32 + nj * 16 + lr;
#pragma unroll
                for (int r = 0; r < 4; ++r) {
                    int m = m0 + wm * 128 + mi * 16 + lq * 4 + r;
                    float h = acc[mi][nj][r];         // hidden
                    float g = acc[mi][nj + 2][r];     // gate, same d
                    float eg  = __expf(g);
                    float c   = fast_rcp(1.0f + eg);  // sigma(-g)
                    float z   = eg * c;               // sigma(g)
                    float enh = __expf(-h);
                    float sh  = fast_rcp(1.0f + enh); // sigma(h)
                    float gh  = (h >= 0.0f) ? (h + 0.5f) : sh;
                    float v   = z * gh;
                    cvb[(size_t)m * D_ + d] = __floats2half2_rn(c, v);
                    V4 = fmaf(c, V4, v);              // compose ascending r
                    C4 *= c;
                }
                float Ca = __shfl_xor(C4, 16), Va = __shfl_xor(V4, 16);
                float Clo = (lq & 1) ? Ca : C4, Vlo = (lq & 1) ? Va : V4;
                float Chi = (lq & 1) ? C4 : Ca, Vhi = (lq & 1) ? V4 : Va;
                float C2 = Clo * Chi, V2 = fmaf(Chi, Vlo, Vhi);
                float Cb = __shfl_xor(C2, 32), Vb = __shfl_xor(V2, 32);
                float Cl2 = (lq & 2) ? Cb : C2, Vl2 = (lq & 2) ? Vb : V2;
                float Ch2 = (lq & 2) ? C2 : Cb, Vh2 = (lq & 2) ? V2 : Vb;
                C16[hf][nj] = Cl2 * Ch2;
                V16[hf][nj] = fmaf(Ch2, Vl2, Vh2);
            }
        }
        if (lq == 0) {
            const int chunkg = (m0 + wm * 128 + mp * 32) >> 5;  // global chunk
#pragma unroll
            for (int nj = 0; nj < 2; ++nj) {
                float C32 = C16[0][nj] * C16[1][nj];
                float V32 = fmaf(C16[1][nj], V16[0][nj], V16[1][nj]);
                const int d = d0 + wn * 32 + nj * 16 + lr;
                float2 st; st.x = C32; st.y = V32;
                CVagg[(size_t)chunkg * D_ + d] = st;
            }
        }
    }
}

// ---------------------------------------------------------------------------
// Kernel 3: scan across chunks (128 FMA steps, tiny). P[c] = h at chunk entry.
// ---------------------------------------------------------------------------
__global__ __launch_bounds__(256) void chunk_scan(
    const float2* __restrict__ CVagg, float* __restrict__ P)
{
    const int d = blockIdx.x * 256 + threadIdx.x;
    const int b = blockIdx.z;
    float h = 0.0f;
    for (int c = 0; c < NC_; ++c) {
        size_t o = ((size_t)b * NC_ + c) * D_ + d;
        P[o] = h;
        float2 cv = CVagg[o];
        h = fmaf(cv.x, h, cv.y);
    }
}

// ---------------------------------------------------------------------------
// Kernel 4: apply — h = fma(c, h, v) from chunk-entry prefix.
// Nontemporal: cvb read-once here; out write-once, never re-read.
// ---------------------------------------------------------------------------
__global__ __launch_bounds__(256) void chunk_apply(
    const unsigned long long* __restrict__ cvw,  // half2-pairs as u64
    const float* __restrict__ P, float* __restrict__ out)
{
    const int d = (blockIdx.x * 256 + threadIdx.x) * 2;
    const int c = blockIdx.y;
    const int b = blockIdx.z;
    size_t base2 = (((size_t)(b * S_ + c * L_)) * D_ + d) >> 1;  // u64 units
    float2 h2 = *(const float2*)(P + ((size_t)b * NC_ + c) * D_ + d);
    float h0 = h2.x, h1 = h2.y;
    unsigned long long* outp = (unsigned long long*)out;
    union Cvt { unsigned long long ull; uint2 u2; float2 f2; };
#pragma unroll
    for (int s = 0; s < L_; ++s) {
        Cvt in;
        in.ull = __builtin_nontemporal_load(cvw + base2 + (size_t)s * (D_ / 2));
        float2 p0 = __half22float2(*(const __half2*)&in.u2.x);
        float2 p1 = __half22float2(*(const __half2*)&in.u2.y);
        h0 = fmaf(p0.x, h0, p0.y);
        h1 = fmaf(p1.x, h1, p1.y);
        Cvt o;
        o.f2.x = h0; o.f2.y = h1;
        __builtin_nontemporal_store(o.ull, outp + base2 + (size_t)s * (D_ / 2));
    }
}

extern "C" void kernel_launch(void* const* d_in, const int* in_sizes, int n_in,
                              void* d_out, int out_size, void* d_ws, size_t ws_size,
                              hipStream_t stream) {
    const float* x = (const float*)d_in[0];   // [B,S,D] fp32
    const float* W = (const float*)d_in[1];   // [2D,D] fp32
    float* out = (float*)d_out;               // [B,S,D] fp32

    float2* CVagg = (float2*)d_ws;                             // B*NC*D float2
    float*  P     = (float*)(CVagg + (size_t)B_ * NC_ * D_);
    __half2* cvb  = (__half2*)(P + (size_t)B_ * NC_ * D_);     // M*D half2
    unsigned short* xb = (unsigned short*)(cvb + (size_t)M_ * D_);  // M*K bf16
    unsigned short* Wb = xb + (size_t)M_ * K_;                      // 2D*K bf16

    const int n8x = M_ * K_ / 8;          // 2,097,152
    const int n8w = 2 * D_ * K_ / 8;      // 262,144
    to_bf16_both<<<(n8x + n8w + 255) / 256, 256, 0, stream>>>(x, W, xb, Wb, n8x, n8w);

    // 512 wgs: 64 m-tiles x 8 d-tiles, XCD-swizzled in-kernel
    gemm_pointwise<<<512, 512, 0, stream>>>(xb, Wb, cvb, CVagg);

    dim3 g3(D_ / 256, 1, B_);      // 4 x 1 x 4
    chunk_scan<<<g3, 256, 0, stream>>>(CVagg, P);

    dim3 g2(D_ / 512, NC_, B_);    // 2 x 128 x 4
    chunk_apply<<<g2, 256, 0, stream>>>((const unsigned long long*)cvb, P, out);
}

// Round 15
// 123.309 us; speedup vs baseline: 1.3548x; 1.3548x over previous
//
#include <hip/hip_runtime.h>
#include <hip/hip_bf16.h>
#include <hip/hip_fp16.h>
#include <math.h>

#define B_  4
#define S_  4096
#define D_  1024
#define M_  (B_ * S_)   // 16384 rows
#define K_  D_          // 1024 reduction
#define L_  32          // scan chunk length
#define NC_ (S_ / L_)   // 128 chunks per sequence
#define NKT 16          // K_/64 K-tiles (BK=64)

typedef __attribute__((ext_vector_type(8))) short          bf16x8;
typedef __attribute__((ext_vector_type(8))) unsigned short u16x8;
typedef __attribute__((ext_vector_type(4))) float          f32x4;

__device__ __forceinline__ unsigned short f2bf(float f) {
    union { __hip_bfloat16 h; unsigned short u; } cv;
    cv.h = __float2bfloat16(f);
    return cv.u;
}

__device__ __forceinline__ float fast_rcp(float x) {
#if __has_builtin(__builtin_amdgcn_rcpf)
    return __builtin_amdgcn_rcpf(x);
#else
    return 1.0f / x;
#endif
}

__device__ __forceinline__ void stage16(const unsigned short* src, char* dst) {
    __builtin_amdgcn_global_load_lds(
        (const __attribute__((address_space(1))) unsigned int*)src,
        (__attribute__((address_space(3))) unsigned int*)dst, 16, 0, 0);
}

// ---------------------------------------------------------------------------
// Kernel 0: fp32 -> bf16 pre-convert, x and W in ONE launch
// ---------------------------------------------------------------------------
__global__ __launch_bounds__(256) void to_bf16_both(
    const float* __restrict__ x, const float* __restrict__ W,
    unsigned short* __restrict__ xb, unsigned short* __restrict__ Wb,
    int n8x, int n8w)
{
    int i = blockIdx.x * 256 + threadIdx.x;
    const float* src;
    unsigned short* dst;
    int j;
    if (i < n8x) { src = x; dst = xb; j = i; }
    else {
        j = i - n8x;
        if (j >= n8w) return;
        src = W; dst = Wb;
    }
    const float4* p = (const float4*)src + (size_t)j * 2;
    float4 a = p[0], b = p[1];
    u16x8 o;
    o[0] = f2bf(a.x); o[1] = f2bf(a.y); o[2] = f2bf(a.z); o[3] = f2bf(a.w);
    o[4] = f2bf(b.x); o[5] = f2bf(b.y); o[6] = f2bf(b.z); o[7] = f2bf(b.w);
    *(u16x8*)(dst + (size_t)j * 8) = o;
}

// ---------------------------------------------------------------------------
// Kernel 1: round-12 champion GEMM (78us, MfmaUtil ~36, 0 bank conflicts):
// BM=256, BN=128d x {h,g}, BK=64, 8 waves (2M x 4N), wave tile 128m x 64c,
// 2-deep LDS (2 x 64KB), 8-phase schedule, 16x16x32 MFMA, global_load_lds
// staging for both operands, swizzle involution slot^=(row>>1)&3 on BOTH
// stage-source and read. Fused linear-domain pointwise
// (c = sigma(-g), v = sigma(g)*g(h)) + per-32-row chunk-(C,V) reduction.
//
// GEMM plateau note (rounds 4-14): 8 structural variants (2-barrier,
// 4-deep counted vmcnt, 8-phase, 2-blk/CU 3-deep, 128x128 wave tile,
// 32x32x16 MFMA, in-GEMM A-convert, B-from-global) all land at 36-38%
// MfmaUtil or worse. The binding constraint is the CU-shared LDS read
// pipe (24 ds_read_b128/thread/K-tile) co-equal with the MFMA pipe at
// every feasible wave-tile/occupancy point for K=1024.
// ---------------------------------------------------------------------------
__global__ __launch_bounds__(512, 2) void gemm_pointwise(
    const unsigned short* __restrict__ xb, const unsigned short* __restrict__ Wb,
    __half2* __restrict__ cvb, float2* __restrict__ CVagg)
{
    __shared__ char lds[131072];   // 2 x 64KB

    const int th   = threadIdx.x;
    const int lane = th & 63;
    const int wave = th >> 6;
    const int wm = wave >> 2;      // 0..1 -> m offset 0/128
    const int wn = wave & 3;       // 0..3 -> d offset 32*wn

    const int wg  = blockIdx.x;                    // 512 wgs, 8 XCDs
    const int swz = (wg & 7) * 64 + (wg >> 3);     // bijective XCD swizzle
    const int m0 = (swz >> 3) * 256;
    const int d0 = (swz & 7) * 128;

    f32x4 acc[8][4];
#pragma unroll
    for (int i = 0; i < 8; ++i)
#pragma unroll
        for (int j = 0; j < 4; ++j)
            acc[i][j] = (f32x4){0.f, 0.f, 0.f, 0.f};

    // staging: 512 thr x 16B = 8KB = 128 rows per round; 8 rounds per K-tile
    const int srow = th >> 2;                               // 0..127
    const int scol = (((th & 3) ^ ((th >> 3) & 3)) * 8);    // pre-swizzled col
    const unsigned short* srcA  = xb + (size_t)(m0 + srow)       * K_ + scol;
    const unsigned short* srcA2 = xb + (size_t)(m0 + 128 + srow) * K_ + scol;
    const unsigned short* srcBh = Wb + (size_t)(d0 + srow)       * K_ + scol;
    const unsigned short* srcBg = Wb + (size_t)(D_ + d0 + srow)  * K_ + scol;
    char* const wuo = lds + wave * 1024;   // wave-uniform LDS dest base

    const int lr = lane & 15;
    const int lq = lane >> 4;
    const int lkb = ((lq ^ ((lr >> 1) & 3)) * 16);            // swizzled slot
    const int aoffb = (wm * 128 + lr) * 64 + lkb;             // A frag base
    const int boffb = 32768 + (wn * 32 + lr) * 64 + lkb;      // B frag base

    bf16x8 Aa[4], Ab[4], Ba[4], Bb[4];

#define BAR()  asm volatile("s_barrier" ::: "memory")
#define LGK0() asm volatile("s_waitcnt lgkmcnt(0)" ::: "memory")
#define VM0()  asm volatile("s_waitcnt vmcnt(0)" ::: "memory")

#define CLUSTER(base, AF, BF) do {                                        \
    __builtin_amdgcn_s_setprio(1);                                        \
    _Pragma("unroll")                                                     \
    for (int i_ = 0; i_ < 4; ++i_)                                        \
        _Pragma("unroll")                                                 \
        for (int j_ = 0; j_ < 4; ++j_)                                    \
            acc[(base) + i_][j_] = __builtin_amdgcn_mfma_f32_16x16x32_bf16(\
                AF[i_], BF[j_], acc[(base) + i_][j_], 0, 0, 0);           \
    __builtin_amdgcn_s_setprio(0);                                        \
  } while (0)

    // prologue: stage tile 0 into buf0, drain, read phase-0 frags
    stage16(srcA,       wuo + 0);
    stage16(srcA2,      wuo + 8192);
    stage16(srcA  + 32, wuo + 16384);
    stage16(srcA2 + 32, wuo + 24576);
    stage16(srcBh,      wuo + 32768);
    stage16(srcBg,      wuo + 40960);
    stage16(srcBh + 32, wuo + 49152);
    stage16(srcBg + 32, wuo + 57344);
    VM0();
    BAR();
    {
        const char* bc = lds;
#pragma unroll
        for (int i = 0; i < 4; ++i)
            Aa[i] = *(const bf16x8*)(bc + aoffb + i * 1024);
#pragma unroll
        for (int j = 0; j < 2; ++j) {
            Ba[j]     = *(const bf16x8*)(bc + boffb + j * 1024);
            Ba[j + 2] = *(const bf16x8*)(bc + boffb + 8192 + j * 1024);
        }
    }

#pragma unroll 1
    for (int t = 0; t < NKT; ++t) {
        const char* bc  = lds + (t & 1) * 65536;        // compute buf (read)
        char*       bn  = wuo + ((t + 1) & 1) * 65536;  // next buf (stage dest)
        const char* bnr = lds + ((t + 1) & 1) * 65536;  // next buf (read)
        const int kof = (t + 1) * 64;
        const bool pre = (t < NKT - 1);

        // ---- phase 0: MFMA acc[0..3] = A(mh0,k0) x B(k0) ----
#pragma unroll
        for (int i = 0; i < 4; ++i)
            Ab[i] = *(const bf16x8*)(bc + aoffb + 4096 + i * 1024);    // (mh1,k0)
        if (pre) {
            stage16(srcA  + kof,      bn + 0);
            stage16(srcA2 + kof,      bn + 8192);
            stage16(srcA  + kof + 32, bn + 16384);
            stage16(srcA2 + kof + 32, bn + 24576);
        }
        BAR(); LGK0();
        CLUSTER(0, Aa, Ba);
        BAR();

        // ---- phase 1: MFMA acc[4..7] = A(mh1,k0) x B(k0) ----
#pragma unroll
        for (int i = 0; i < 4; ++i)
            Aa[i] = *(const bf16x8*)(bc + aoffb + 16384 + i * 1024);   // (mh0,k1)
#pragma unroll
        for (int j = 0; j < 2; ++j) {
            Bb[j]     = *(const bf16x8*)(bc + boffb + 16384 + j * 1024);         // B(k1) h
            Bb[j + 2] = *(const bf16x8*)(bc + boffb + 16384 + 8192 + j * 1024);  // B(k1) g
        }
        if (pre) {
            stage16(srcBh + kof,      bn + 32768);
            stage16(srcBg + kof,      bn + 40960);
            stage16(srcBh + kof + 32, bn + 49152);
            stage16(srcBg + kof + 32, bn + 57344);
        }
        BAR(); LGK0();
        CLUSTER(4, Ab, Ba);
        BAR();

        // ---- phase 2: MFMA acc[0..3] = A(mh0,k1) x B(k1) ----
#pragma unroll
        for (int i = 0; i < 4; ++i)
            Ab[i] = *(const bf16x8*)(bc + aoffb + 4096 + 16384 + i * 1024);  // (mh1,k1)
        BAR(); LGK0();
        CLUSTER(0, Aa, Bb);
        BAR();

        // ---- phase 3: cross-buf sync, prefetch next frags, last cluster ----
        VM0();           // t+1's 8 loads issued >=2 phases ago -> cheap drain
        BAR();           // buf[(t+1)&1] now globally valid
        if (pre) {       // issue next tile's phase-0 frag reads BEFORE MFMAs
#pragma unroll
            for (int i = 0; i < 4; ++i)
                Aa[i] = *(const bf16x8*)(bnr + aoffb + i * 1024);
#pragma unroll
            for (int j = 0; j < 2; ++j) {
                Ba[j]     = *(const bf16x8*)(bnr + boffb + j * 1024);
                Ba[j + 2] = *(const bf16x8*)(bnr + boffb + 8192 + j * 1024);
            }
        }
        CLUSTER(4, Ab, Bb);
        // no trailing barrier: next phase-0 stages into buf[t&1], which no
        // wave reads after phase 2's closing barrier (phase 3 = regs + bnr)
    }
#undef CLUSTER
#undef BAR
#undef LGK0
#undef VM0

    // ---- epilogue: pointwise + cvb store + fused chunk-(C,V) reduction ----
    // C/D: col = lane&15 (d), row = lq*4 + reg (m). Chunk (32 rows) = mi
    // pair; compose r-fold -> lq-compose (shfl_xor 16,32) -> mi-pair.
#pragma unroll
    for (int mp = 0; mp < 4; ++mp) {          // mi pair (2mp, 2mp+1)
        float C16[2][2], V16[2][2];
#pragma unroll
        for (int hf = 0; hf < 2; ++hf) {
            const int mi = mp * 2 + hf;
#pragma unroll
            for (int nj = 0; nj < 2; ++nj) {
                float C4 = 1.0f, V4 = 0.0f;
                const int d = d0 + wn * 32 + nj * 16 + lr;
#pragma unroll
                for (int r = 0; r < 4; ++r) {
                    int m = m0 + wm * 128 + mi * 16 + lq * 4 + r;
                    float h = acc[mi][nj][r];         // hidden
                    float g = acc[mi][nj + 2][r];     // gate, same d
                    float eg  = __expf(g);
                    float c   = fast_rcp(1.0f + eg);  // sigma(-g)
                    float z   = eg * c;               // sigma(g)
                    float enh = __expf(-h);
                    float sh  = fast_rcp(1.0f + enh); // sigma(h)
                    float gh  = (h >= 0.0f) ? (h + 0.5f) : sh;
                    float v   = z * gh;
                    cvb[(size_t)m * D_ + d] = __floats2half2_rn(c, v);
                    V4 = fmaf(c, V4, v);              // compose ascending r
                    C4 *= c;
                }
                float Ca = __shfl_xor(C4, 16), Va = __shfl_xor(V4, 16);
                float Clo = (lq & 1) ? Ca : C4, Vlo = (lq & 1) ? Va : V4;
                float Chi = (lq & 1) ? C4 : Ca, Vhi = (lq & 1) ? V4 : Va;
                float C2 = Clo * Chi, V2 = fmaf(Chi, Vlo, Vhi);
                float Cb = __shfl_xor(C2, 32), Vb = __shfl_xor(V2, 32);
                float Cl2 = (lq & 2) ? Cb : C2, Vl2 = (lq & 2) ? Vb : V2;
                float Ch2 = (lq & 2) ? C2 : Cb, Vh2 = (lq & 2) ? V2 : Vb;
                C16[hf][nj] = Cl2 * Ch2;
                V16[hf][nj] = fmaf(Ch2, Vl2, Vh2);
            }
        }
        if (lq == 0) {
            const int chunkg = (m0 + wm * 128 + mp * 32) >> 5;  // global chunk
#pragma unroll
            for (int nj = 0; nj < 2; ++nj) {
                float C32 = C16[0][nj] * C16[1][nj];
                float V32 = fmaf(C16[1][nj], V16[0][nj], V16[1][nj]);
                const int d = d0 + wn * 32 + nj * 16 + lr;
                float2 st; st.x = C32; st.y = V32;
                CVagg[(size_t)chunkg * D_ + d] = st;
            }
        }
    }
}

// ---------------------------------------------------------------------------
// Kernel 3: scan across chunks (128 FMA steps, tiny). P[c] = h at chunk entry.
// ---------------------------------------------------------------------------
__global__ __launch_bounds__(256) void chunk_scan(
    const float2* __restrict__ CVagg, float* __restrict__ P)
{
    const int d = blockIdx.x * 256 + threadIdx.x;
    const int b = blockIdx.z;
    float h = 0.0f;
    for (int c = 0; c < NC_; ++c) {
        size_t o = ((size_t)b * NC_ + c) * D_ + d;
        P[o] = h;
        float2 cv = CVagg[o];
        h = fmaf(cv.x, h, cv.y);
    }
}

// ---------------------------------------------------------------------------
// Kernel 4: apply — h = fma(c, h, v). 16B/lane nontemporal loads/stores
// (4 d-channels per thread; 256 thr x 4 = D exactly, one block per (c,b)).
// cvb read-once, out write-once -> both nontemporal.
// ---------------------------------------------------------------------------
__global__ __launch_bounds__(256) void chunk_apply(
    const unsigned long long* __restrict__ cvw,  // half2-pairs as u64
    const float* __restrict__ P, float* __restrict__ out)
{
    const int d = threadIdx.x * 4;
    const int c = blockIdx.y;
    const int b = blockIdx.z;
    size_t base2 = (((size_t)(b * S_ + c * L_)) * D_ + d) >> 1;  // u64 units
    const float4* p4p = (const float4*)(P + ((size_t)b * NC_ + c) * D_ + d);
    float4 hp = *p4p;
    float h0 = hp.x, h1 = hp.y, h2 = hp.z, h3 = hp.w;
    unsigned long long* outp = (unsigned long long*)out;
    union Cvt { unsigned long long ull; uint2 u2; float2 f2; };
#pragma unroll
    for (int s = 0; s < L_; ++s) {
        const size_t o2 = base2 + (size_t)s * (D_ / 2);
        Cvt inA, inB;
        inA.ull = __builtin_nontemporal_load(cvw + o2);
        inB.ull = __builtin_nontemporal_load(cvw + o2 + 1);
        float2 p0 = __half22float2(*(const __half2*)&inA.u2.x);
        float2 p1 = __half22float2(*(const __half2*)&inA.u2.y);
        float2 p2 = __half22float2(*(const __half2*)&inB.u2.x);
        float2 p3 = __half22float2(*(const __half2*)&inB.u2.y);
        h0 = fmaf(p0.x, h0, p0.y);
        h1 = fmaf(p1.x, h1, p1.y);
        h2 = fmaf(p2.x, h2, p2.y);
        h3 = fmaf(p3.x, h3, p3.y);
        Cvt oA, oB;
        oA.f2.x = h0; oA.f2.y = h1;
        oB.f2.x = h2; oB.f2.y = h3;
        __builtin_nontemporal_store(oA.ull, outp + o2);
        __builtin_nontemporal_store(oB.ull, outp + o2 + 1);
    }
}

extern "C" void kernel_launch(void* const* d_in, const int* in_sizes, int n_in,
                              void* d_out, int out_size, void* d_ws, size_t ws_size,
                              hipStream_t stream) {
    const float* x = (const float*)d_in[0];   // [B,S,D] fp32
    const float* W = (const float*)d_in[1];   // [2D,D] fp32
    float* out = (float*)d_out;               // [B,S,D] fp32

    float2* CVagg = (float2*)d_ws;                             // B*NC*D float2
    float*  P     = (float*)(CVagg + (size_t)B_ * NC_ * D_);
    __half2* cvb  = (__half2*)(P + (size_t)B_ * NC_ * D_);     // M*D half2
    unsigned short* xb = (unsigned short*)(cvb + (size_t)M_ * D_);  // M*K bf16
    unsigned short* Wb = xb + (size_t)M_ * K_;                      // 2D*K bf16

    const int n8x = M_ * K_ / 8;          // 2,097,152
    const int n8w = 2 * D_ * K_ / 8;      // 262,144
    to_bf16_both<<<(n8x + n8w + 255) / 256, 256, 0, stream>>>(x, W, xb, Wb, n8x, n8w);

    // 512 wgs: 64 m-tiles x 8 d-tiles, XCD-swizzled in-kernel
    gemm_pointwise<<<512, 512, 0, stream>>>(xb, Wb, cvb, CVagg);

    dim3 g3(D_ / 256, 1, B_);      // 4 x 1 x 4
    chunk_scan<<<g3, 256, 0, stream>>>(CVagg, P);

    dim3 g2(1, NC_, B_);           // 1 x 128 x 4
    chunk_apply<<<g2, 256, 0, stream>>>((const unsigned long long*)cvb, P, out);
}